// Round 14
// baseline (347.764 us; speedup 1.0000x reference)
//
#include <hip/hip_runtime.h>
#include <hip/hip_bf16.h>
#include <math.h>

#define NEG_ 16
#define PRED_ 5
#define EPS_ 1e-11f
#define LDW 18    // logit tile row stride (floats)
#define GSTR 272  // score LDS gather-row stride in shorts (544 B)
#define ASTR 72   // gemm LDS tile row stride in shorts (144 B = 9x16B, odd -> conflict-free b128)

typedef __attribute__((ext_vector_type(8))) short bf16x8;
typedef __attribute__((ext_vector_type(4))) float f32x4;

static __device__ __forceinline__ unsigned short f2bu(float f) {
  __hip_bfloat16 h = __float2bfloat16(f);
  return *(unsigned short*)&h;
}

// ws layout (bytes):
//   Zp bf16 [16384][256] : 0         rows q*64+b; rows<2048 (h<2) never touched
//   Cb bf16 [16384][256] : 8388608   rows>=14336 never touched
//   Wb bf16 [5][256][256]: 16777216
//   Yb bf16 [5][14336][256]: 17432576  rows>=Mk unused per k
//   Lk f32  [5][14336]   : 54132736  tails [Mk,14336) NEVER read -> no memset
// Purity: every read is of data written earlier in this launch.

// ---- prep: transpose z/c (+cast) with 128B-coalesced writes, + W cast ----
// grid (256, 8, 2), block 256. by<7: transpose 64p x 32q tile; by==7: W cast.
__global__ __launch_bounds__(256) void prep_all(
    const float* __restrict__ z, const float* __restrict__ c,
    const float* __restrict__ Wk,
    unsigned short* __restrict__ Zp, unsigned short* __restrict__ Cb,
    unsigned short* __restrict__ Wb) {
  __shared__ float tile[32][65];   // [q][p]
  const int t = threadIdx.x;
  if (blockIdx.y == 7) {
    int ib = blockIdx.z * 256 + blockIdx.x;   // 0..511; need 320
    if (ib < 320) {
      int i = ib * 256 + t;
      float4 v = ((const float4*)Wk)[i];
      ushort4 o;
      o.x = f2bu(v.x); o.y = f2bu(v.y); o.z = f2bu(v.z); o.w = f2bu(v.w);
      ((ushort4*)Wb)[i] = o;
    }
    return;
  }
  const float* in = blockIdx.z ? c : z;
  unsigned short* out = blockIdx.z ? Cb : Zp;
  const int p0 = blockIdx.x * 64;                          // [0,16384)
  const int q0 = blockIdx.y * 32 + (blockIdx.z ? 0 : 32);  // z:[32,256) c:[0,224)
  const int tx = t & 31, ty = t >> 5;       // (32,8)
#pragma unroll
  for (int r = 0; r < 64; r += 8)           // reads: 128B contiguous per p-row
    tile[tx][ty + r] = in[(size_t)(p0 + ty + r) * 256 + q0 + tx];
  __syncthreads();
  const int pp = t & 63, wq = t >> 6;       // (64,4)
#pragma unroll
  for (int r = 0; r < 32; r += 4)           // writes: 128B contiguous per wave
    out[(size_t)(q0 + wq + r) * 16384 + p0 + pp] = f2bu(tile[wq + r][pp]);
}

// ---- LDS-staged MFMA GEMM: 128x128 tile, BK=64 (R13, kept) ----
__global__ __launch_bounds__(256) void gemm_all(
    const unsigned short* __restrict__ Zp, const unsigned short* __restrict__ Wb,
    unsigned short* __restrict__ Yb) {
  const int kk = blockIdx.z;
  const int Mk = (14 - kk) * 1024;
  const int m0b = blockIdx.y * 128;
  if (m0b >= Mk) return;
  const unsigned short* A = Zp + (size_t)(kk + 2) * 1024 * 256;
  const unsigned short* Wm = Wb + (size_t)kk * 65536;
  unsigned short* Y = Yb + (size_t)kk * 14336 * 256;
  __shared__ unsigned short As[128 * ASTR];
  __shared__ unsigned short Bs[128 * ASTR];
  const int t = threadIdx.x;
  const int wid = t >> 6, lane = t & 63;
  const int wm = wid >> 1, wn = wid & 1;
  const int l15 = lane & 15, quad = lane >> 4;
  const int n0 = blockIdx.x * 128;
  const int srow = t >> 1, shalf = t & 1;
  const unsigned short* ga = A + (size_t)(m0b + srow) * 256 + shalf * 32;
  const unsigned short* gb = Wm + (size_t)(n0 + srow) * 256 + shalf * 32;
  unsigned short* wa = As + srow * ASTR + shalf * 32;
  unsigned short* wb = Bs + srow * ASTR + shalf * 32;
  f32x4 acc[4][4] = {};
  bf16x8 ra[4], rb[4];
#pragma unroll
  for (int cs = 0; cs < 4; ++cs) {
    ra[cs] = *(const bf16x8*)(ga + cs * 8);
    rb[cs] = *(const bf16x8*)(gb + cs * 8);
  }
#pragma unroll
  for (int ki = 0; ki < 4; ++ki) {
    __syncthreads();
#pragma unroll
    for (int cs = 0; cs < 4; ++cs) {
      *(bf16x8*)(wa + cs * 8) = ra[cs];
      *(bf16x8*)(wb + cs * 8) = rb[cs];
    }
    __syncthreads();
    if (ki < 3) {
      const int k1 = (ki + 1) * 64;
#pragma unroll
      for (int cs = 0; cs < 4; ++cs) {
        ra[cs] = *(const bf16x8*)(ga + k1 + cs * 8);
        rb[cs] = *(const bf16x8*)(gb + k1 + cs * 8);
      }
    }
#pragma unroll
    for (int ks = 0; ks < 2; ++ks) {
      bf16x8 af[4], bf[4];
#pragma unroll
      for (int tm = 0; tm < 4; ++tm)
        af[tm] = *(const bf16x8*)(As + (wm * 64 + tm * 16 + l15) * ASTR + ks * 32 + quad * 8);
#pragma unroll
      for (int tn = 0; tn < 4; ++tn)
        bf[tn] = *(const bf16x8*)(Bs + (wn * 64 + tn * 16 + l15) * ASTR + ks * 32 + quad * 8);
#pragma unroll
      for (int tm = 0; tm < 4; ++tm)
#pragma unroll
        for (int tn = 0; tn < 4; ++tn)
          acc[tm][tn] = __builtin_amdgcn_mfma_f32_16x16x32_bf16(
              af[tm], bf[tn], acc[tm][tn], 0, 0, 0);
    }
  }
#pragma unroll
  for (int tm = 0; tm < 4; ++tm)
#pragma unroll
    for (int tn = 0; tn < 4; ++tn)
#pragma unroll
      for (int r = 0; r < 4; ++r)
        Y[(size_t)(m0b + wm * 64 + tm * 16 + quad * 4 + r) * 256 +
          n0 + wn * 64 + tn * 16 + l15] = f2bu(acc[tm][tn][r]);
}

// ---- fused scoring: wave-contiguous gathers + depth-2 prefetch ring ----
__global__ __launch_bounds__(256) void score_all(
    const unsigned short* __restrict__ Yb, const unsigned short* __restrict__ Cb,
    const int* __restrict__ r1, const int* __restrict__ r2,
    const int* __restrict__ r3, const int* __restrict__ r4,
    const int* __restrict__ r5, float* __restrict__ Lk) {
  __shared__ __align__(16) unsigned short gbuf[4][16 * GSTR];
  __shared__ float L[16 * LDW];
  const int wv = threadIdx.x >> 6, lane = threadIdx.x & 63;
  const int gid = blockIdx.x;
  int kk, base;
  if (gid < 896)       { kk = 0; base = 0; }
  else if (gid < 1728) { kk = 1; base = 896; }
  else if (gid < 2496) { kk = 2; base = 1728; }
  else if (gid < 3200) { kk = 3; base = 2496; }
  else                 { kk = 4; base = 3200; }
  const int Mk = (14 - kk) * 1024;
  const int m0 = (gid - base) * 16;
  const int* ridx = kk == 0 ? r1 : kk == 1 ? r2 : kk == 2 ? r3 : kk == 3 ? r4 : r5;
  const unsigned short* Y = Yb + (size_t)kk * 14336 * 256;
  const int l15 = lane & 15, quad = lane >> 4;
  const int half = lane >> 5, ch = lane & 31;
  unsigned short* mybuf = gbuf[wv];

  auto gather = [&](const unsigned short* src, int iv, bf16x8* dst) {
#pragma unroll
    for (int j = 0; j < 8; ++j) {
      int rlo = __shfl(iv, 2 * j);
      int rhi = __shfl(iv, 2 * j + 1);
      int row = half ? rhi : rlo;
      dst[j] = *(const bf16x8*)(src + (size_t)row * 256 + ch * 8);
    }
  };
  auto stage = [&](const bf16x8* g) {
#pragma unroll
    for (int j2 = 0; j2 < 8; ++j2)
      *(bf16x8*)(mybuf + (2 * j2 + half) * GSTR + ch * 8) = g[j2];
  };

  bf16x8 af[8];
  {
    bf16x8 g[8];
    gather(Cb, m0 + l15, g);
    stage(g);
#pragma unroll
    for (int tv = 0; tv < 8; ++tv)
      af[tv] = *(const bf16x8*)(mybuf + l15 * GSTR + quad * 8 + tv * 32);
  }

  const int c0 = (wv == 0) ? 0 : (4 * wv + 1);
  const int nc = (wv == 0) ? 5 : 4;
  auto load_iv = [&](int c) -> int {
    if (c == 0) return m0 + l15;
    int idx = ridx[(m0 + (c - 1)) * NEG_ + l15];
    return idx < 0 ? 0 : (idx >= Mk ? Mk - 1 : idx);
  };

  // depth-2 prefetch ring: two gathers (16 loads) in flight per wave
  bf16x8 ring[3][8];
  gather(Y, load_iv(c0), ring[0]);
  gather(Y, load_iv(c0 + 1), ring[1]);   // nc>=4 always, safe
  for (int j = 0; j < nc; ++j) {
    if (j + 2 < nc) gather(Y, load_iv(c0 + j + 2), ring[(j + 2) % 3]);
    stage(ring[j % 3]);
    f32x4 acc = {};
#pragma unroll
    for (int tv = 0; tv < 8; ++tv) {
      bf16x8 bf = *(const bf16x8*)(mybuf + l15 * GSTR + quad * 8 + tv * 32);
      acc = __builtin_amdgcn_mfma_f32_16x16x32_bf16(af[tv], bf, acc, 0, 0, 0);
    }
    const int c = c0 + j;
    if (c == 0) {
#pragma unroll
      for (int r = 0; r < 4; ++r)
        if (l15 == quad * 4 + r) L[(quad * 4 + r) * LDW] = acc[r];
    } else {
      const int i = c - 1;
      if (quad == (i >> 2)) L[i * LDW + 1 + l15] = acc[i & 3];
    }
  }
  __syncthreads();
  if (threadIdx.x < 16) {
    float mainv = L[threadIdx.x * LDW];
    float mx = mainv;
    float nv[NEG_];
#pragma unroll
    for (int n = 0; n < NEG_; ++n) {
      nv[n] = L[threadIdx.x * LDW + 1 + n];
      mx = fmaxf(mx, nv[n]);
    }
    float num = __expf(mainv - mx);
    float se = num;
#pragma unroll
    for (int n = 0; n < NEG_; ++n) se += __expf(nv[n] - mx);
    Lk[kk * 14336 + m0 + threadIdx.x] = -logf(num / se + EPS_);
  }
}

// ---- patchwise loss + counts (blocks 0..63) + total (block 64) ----
__global__ __launch_bounds__(256) void finalize_pl(
    const float* __restrict__ Lk, float* __restrict__ out) {
  if (blockIdx.x < 64) {
    int idx = blockIdx.x * 256 + threadIdx.x;   // b*256 + h*16 + w
    int b = idx >> 8, h = (idx >> 4) & 15, w = idx & 15;
    float v = 0.f;
#pragma unroll
    for (int kk = 0; kk < PRED_; ++kk) {
      int off = kk + 2;
      if (h >= off)      v += Lk[kk * 14336 + ((h - off) * 16 + w) * 64 + b];
      if (h <= 15 - off) v += Lk[kk * 14336 + (h * 16 + w) * 64 + b];
    }
    out[1 + idx] = v;
    if (idx < 256) {
      int hh = idx >> 4;
      float cnt = 0.f;
#pragma unroll
      for (int off = 2; off <= 6; ++off)
        cnt += (hh >= off ? 1.f : 0.f) + (hh <= 15 - off ? 1.f : 0.f);
      out[1 + 16384 + idx] = cnt;
    }
  } else {
    __shared__ float red[256];
    const int t = threadIdx.x;
    float local = 0.f;
#pragma unroll
    for (int kk = 0; kk < PRED_; ++kk) {
      const int Mk = (14 - kk) * 1024;
      const float scale = 1.0f / (5120.0f * (float)(14 - kk));
      for (int e = t; e < Mk; e += 256)
        local += Lk[kk * 14336 + e] * scale;
    }
    red[t] = local;
    __syncthreads();
    for (int s = 128; s; s >>= 1) {
      if (t < s) red[t] += red[t + s];
      __syncthreads();
    }
    if (t == 0) out[0] = red[0];
  }
}

extern "C" void kernel_launch(void* const* d_in, const int* in_sizes, int n_in,
                              void* d_out, int out_size, void* d_ws, size_t ws_size,
                              hipStream_t stream) {
  const float* z  = (const float*)d_in[0];
  const float* c  = (const float*)d_in[1];
  const float* Wk = (const float*)d_in[2];
  float* out = (float*)d_out;
  char* wsb = (char*)d_ws;
  unsigned short* Zp = (unsigned short*)(wsb);
  unsigned short* Cb = (unsigned short*)(wsb + 8388608);
  unsigned short* Wb = (unsigned short*)(wsb + 16777216);
  unsigned short* Yb = (unsigned short*)(wsb + 17432576);
  float*          Lk = (float*)(wsb + 54132736);

  prep_all<<<dim3(256, 8, 2), 256, 0, stream>>>(z, c, Wk, Zp, Cb, Wb);
  gemm_all<<<dim3(2, 112, PRED_), 256, 0, stream>>>(Zp, Wb, Yb);
  score_all<<<3840, 256, 0, stream>>>(
      Yb, Cb, (const int*)d_in[3], (const int*)d_in[4], (const int*)d_in[5],
      (const int*)d_in[6], (const int*)d_in[7], Lk);
  finalize_pl<<<65, 256, 0, stream>>>(Lk, out);
}

// Round 15
// 183.101 us; speedup vs baseline: 1.8993x; 1.8993x over previous
//
#include <hip/hip_runtime.h>
#include <hip/hip_bf16.h>
#include <math.h>

#define NEG_ 16
#define PRED_ 5
#define EPS_ 1e-11f
#define LDW 18    // logit tile row stride (floats)
#define GSTR 272  // score LDS gather-row stride in shorts (544 B)
#define ASTR 72   // gemm LDS tile row stride in shorts (144 B, odd16 -> conflict-free b128)

typedef __attribute__((ext_vector_type(8))) short bf16x8;
typedef __attribute__((ext_vector_type(4))) float f32x4;

static __device__ __forceinline__ unsigned short f2bu(float f) {
  __hip_bfloat16 h = __float2bfloat16(f);
  return *(unsigned short*)&h;
}

// ws layout (bytes):
//   Zp bf16 [16384][256] : 0         rows q*64+b; rows<2048 (h<2) never touched
//   Cb bf16 [16384][256] : 8388608   rows>=14336 never touched
//   Wb bf16 [5][256][256]: 16777216
//   Yb bf16 [5][14336][256]: 17432576  rows>=Mk unused per k
//   Lk f32  [5][14336]   : 54132736  tails [Mk,14336) NEVER read -> no memset
// Purity: every read is of data written earlier in this launch.

// ---- prep: transpose z/c (+cast) with 128B-coalesced reads AND writes ----
__global__ __launch_bounds__(256) void prep_all(
    const float* __restrict__ z, const float* __restrict__ c,
    const float* __restrict__ Wk,
    unsigned short* __restrict__ Zp, unsigned short* __restrict__ Cb,
    unsigned short* __restrict__ Wb) {
  __shared__ float tile[32][65];   // [q][p]
  const int t = threadIdx.x;
  if (blockIdx.y == 7) {
    int ib = blockIdx.z * 256 + blockIdx.x;   // 0..511; need 320
    if (ib < 320) {
      int i = ib * 256 + t;
      float4 v = ((const float4*)Wk)[i];
      ushort4 o;
      o.x = f2bu(v.x); o.y = f2bu(v.y); o.z = f2bu(v.z); o.w = f2bu(v.w);
      ((ushort4*)Wb)[i] = o;
    }
    return;
  }
  const float* in = blockIdx.z ? c : z;
  unsigned short* out = blockIdx.z ? Cb : Zp;
  const int p0 = blockIdx.x * 64;                          // [0,16384)
  const int q0 = blockIdx.y * 32 + (blockIdx.z ? 0 : 32);  // z:[32,256) c:[0,224)
  const int tx = t & 31, ty = t >> 5;       // (32,8)
#pragma unroll
  for (int r = 0; r < 64; r += 8)
    tile[tx][ty + r] = in[(size_t)(p0 + ty + r) * 256 + q0 + tx];
  __syncthreads();
  const int pp = t & 63, wq = t >> 6;       // (64,4)
#pragma unroll
  for (int r = 0; r < 32; r += 4)
    out[(size_t)(q0 + wq + r) * 16384 + p0 + pp] = f2bu(tile[wq + r][pp]);
}

// ---- LDS-staged MFMA GEMM: 128x128 tile, BK=64 (R13, proven) ----
__global__ __launch_bounds__(256) void gemm_all(
    const unsigned short* __restrict__ Zp, const unsigned short* __restrict__ Wb,
    unsigned short* __restrict__ Yb) {
  const int kk = blockIdx.z;
  const int Mk = (14 - kk) * 1024;
  const int m0b = blockIdx.y * 128;
  if (m0b >= Mk) return;
  const unsigned short* A = Zp + (size_t)(kk + 2) * 1024 * 256;
  const unsigned short* Wm = Wb + (size_t)kk * 65536;
  unsigned short* Y = Yb + (size_t)kk * 14336 * 256;
  __shared__ unsigned short As[128 * ASTR];
  __shared__ unsigned short Bs[128 * ASTR];
  const int t = threadIdx.x;
  const int wid = t >> 6, lane = t & 63;
  const int wm = wid >> 1, wn = wid & 1;
  const int l15 = lane & 15, quad = lane >> 4;
  const int n0 = blockIdx.x * 128;
  const int srow = t >> 1, shalf = t & 1;
  const unsigned short* ga = A + (size_t)(m0b + srow) * 256 + shalf * 32;
  const unsigned short* gb = Wm + (size_t)(n0 + srow) * 256 + shalf * 32;
  unsigned short* wa = As + srow * ASTR + shalf * 32;
  unsigned short* wb = Bs + srow * ASTR + shalf * 32;
  f32x4 acc[4][4] = {};
  bf16x8 ra[4], rb[4];
#pragma unroll
  for (int cs = 0; cs < 4; ++cs) {
    ra[cs] = *(const bf16x8*)(ga + cs * 8);
    rb[cs] = *(const bf16x8*)(gb + cs * 8);
  }
#pragma unroll
  for (int ki = 0; ki < 4; ++ki) {
    __syncthreads();
#pragma unroll
    for (int cs = 0; cs < 4; ++cs) {
      *(bf16x8*)(wa + cs * 8) = ra[cs];
      *(bf16x8*)(wb + cs * 8) = rb[cs];
    }
    __syncthreads();
    if (ki < 3) {
      const int k1 = (ki + 1) * 64;
#pragma unroll
      for (int cs = 0; cs < 4; ++cs) {
        ra[cs] = *(const bf16x8*)(ga + k1 + cs * 8);
        rb[cs] = *(const bf16x8*)(gb + k1 + cs * 8);
      }
    }
#pragma unroll
    for (int ks = 0; ks < 2; ++ks) {
      bf16x8 af[4], bf[4];
#pragma unroll
      for (int tm = 0; tm < 4; ++tm)
        af[tm] = *(const bf16x8*)(As + (wm * 64 + tm * 16 + l15) * ASTR + ks * 32 + quad * 8);
#pragma unroll
      for (int tn = 0; tn < 4; ++tn)
        bf[tn] = *(const bf16x8*)(Bs + (wn * 64 + tn * 16 + l15) * ASTR + ks * 32 + quad * 8);
#pragma unroll
      for (int tm = 0; tm < 4; ++tm)
#pragma unroll
        for (int tn = 0; tn < 4; ++tn)
          acc[tm][tn] = __builtin_amdgcn_mfma_f32_16x16x32_bf16(
              af[tm], bf[tn], acc[tm][tn], 0, 0, 0);
    }
  }
#pragma unroll
  for (int tm = 0; tm < 4; ++tm)
#pragma unroll
    for (int tn = 0; tn < 4; ++tn)
#pragma unroll
      for (int r = 0; r < 4; ++r)
        Y[(size_t)(m0b + wm * 64 + tm * 16 + quad * 4 + r) * 256 +
          n0 + wn * 64 + tn * 16 + l15] = f2bu(acc[tm][tn][r]);
}

// ---- fused scoring: R13 depth-1 pipeline + upfront index precompute ----
__global__ __launch_bounds__(256) void score_all(
    const unsigned short* __restrict__ Yb, const unsigned short* __restrict__ Cb,
    const int* __restrict__ r1, const int* __restrict__ r2,
    const int* __restrict__ r3, const int* __restrict__ r4,
    const int* __restrict__ r5, float* __restrict__ Lk) {
  __shared__ __align__(16) unsigned short gbuf[4][16 * GSTR];
  __shared__ float L[16 * LDW];
  const int wv = threadIdx.x >> 6, lane = threadIdx.x & 63;
  const int gid = blockIdx.x;
  int kk, base;
  if (gid < 896)       { kk = 0; base = 0; }
  else if (gid < 1728) { kk = 1; base = 896; }
  else if (gid < 2496) { kk = 2; base = 1728; }
  else if (gid < 3200) { kk = 3; base = 2496; }
  else                 { kk = 4; base = 3200; }
  const int Mk = (14 - kk) * 1024;
  const int m0 = (gid - base) * 16;
  const int* ridx = kk == 0 ? r1 : kk == 1 ? r2 : kk == 2 ? r3 : kk == 3 ? r4 : r5;
  const unsigned short* Y = Yb + (size_t)kk * 14336 * 256;
  const int l15 = lane & 15, quad = lane >> 4;
  const int half = lane >> 5, ch = lane & 31;
  unsigned short* mybuf = gbuf[wv];

  auto gather = [&](const unsigned short* src, int iv, bf16x8* dst) {
#pragma unroll
    for (int j = 0; j < 8; ++j) {
      int rlo = __shfl(iv, 2 * j);
      int rhi = __shfl(iv, 2 * j + 1);
      int row = half ? rhi : rlo;
      dst[j] = *(const bf16x8*)(src + (size_t)row * 256 + ch * 8);
    }
  };
  auto stage = [&](const bf16x8* g) {
#pragma unroll
    for (int j2 = 0; j2 < 8; ++j2)
      *(bf16x8*)(mybuf + (2 * j2 + half) * GSTR + ch * 8) = g[j2];
  };

  const int c0 = (wv == 0) ? 0 : (4 * wv + 1);
  const int nc = (wv == 0) ? 5 : 4;
  // precompute ALL chain indices upfront: the ridx dword loads issue in
  // parallel here instead of serializing ahead of each gather.
  int iv[5];
#pragma unroll
  for (int j = 0; j < 5; ++j) {
    if (j < nc) {
      const int c = c0 + j;
      if (c == 0) iv[j] = m0 + l15;
      else {
        int idx = ridx[(m0 + (c - 1)) * NEG_ + l15];
        iv[j] = idx < 0 ? 0 : (idx >= Mk ? Mk - 1 : idx);
      }
    } else iv[j] = 0;
  }

  bf16x8 af[8];
  {
    bf16x8 g[8];
    gather(Cb, m0 + l15, g);
    stage(g);
#pragma unroll
    for (int tv = 0; tv < 8; ++tv)
      af[tv] = *(const bf16x8*)(mybuf + l15 * GSTR + quad * 8 + tv * 32);
  }

  bf16x8 g[8], gn[8];
  gather(Y, iv[0], g);
  for (int j = 0; j < nc; ++j) {
    if (j + 1 < nc) gather(Y, iv[j + 1], gn);
    stage(g);
    f32x4 acc = {};
#pragma unroll
    for (int tv = 0; tv < 8; ++tv) {
      bf16x8 bf = *(const bf16x8*)(mybuf + l15 * GSTR + quad * 8 + tv * 32);
      acc = __builtin_amdgcn_mfma_f32_16x16x32_bf16(af[tv], bf, acc, 0, 0, 0);
    }
    const int c = c0 + j;
    if (c == 0) {
#pragma unroll
      for (int r = 0; r < 4; ++r)
        if (l15 == quad * 4 + r) L[(quad * 4 + r) * LDW] = acc[r];
    } else {
      const int i = c - 1;
      if (quad == (i >> 2)) L[i * LDW + 1 + l15] = acc[i & 3];
    }
#pragma unroll
    for (int tv = 0; tv < 8; ++tv) g[tv] = gn[tv];
  }
  __syncthreads();
  if (threadIdx.x < 16) {
    float mainv = L[threadIdx.x * LDW];
    float mx = mainv;
    float nv[NEG_];
#pragma unroll
    for (int n = 0; n < NEG_; ++n) {
      nv[n] = L[threadIdx.x * LDW + 1 + n];
      mx = fmaxf(mx, nv[n]);
    }
    float num = __expf(mainv - mx);
    float se = num;
#pragma unroll
    for (int n = 0; n < NEG_; ++n) se += __expf(nv[n] - mx);
    Lk[kk * 14336 + m0 + threadIdx.x] = -logf(num / se + EPS_);
  }
}

// ---- patchwise loss + counts (blocks 0..63) + total (block 64) ----
__global__ __launch_bounds__(256) void finalize_pl(
    const float* __restrict__ Lk, float* __restrict__ out) {
  if (blockIdx.x < 64) {
    int idx = blockIdx.x * 256 + threadIdx.x;   // b*256 + h*16 + w
    int b = idx >> 8, h = (idx >> 4) & 15, w = idx & 15;
    float v = 0.f;
#pragma unroll
    for (int kk = 0; kk < PRED_; ++kk) {
      int off = kk + 2;
      if (h >= off)      v += Lk[kk * 14336 + ((h - off) * 16 + w) * 64 + b];
      if (h <= 15 - off) v += Lk[kk * 14336 + (h * 16 + w) * 64 + b];
    }
    out[1 + idx] = v;
    if (idx < 256) {
      int hh = idx >> 4;
      float cnt = 0.f;
#pragma unroll
      for (int off = 2; off <= 6; ++off)
        cnt += (hh >= off ? 1.f : 0.f) + (hh <= 15 - off ? 1.f : 0.f);
      out[1 + 16384 + idx] = cnt;
    }
  } else {
    __shared__ float red[256];
    const int t = threadIdx.x;
    float local = 0.f;
#pragma unroll
    for (int kk = 0; kk < PRED_; ++kk) {
      const int Mk = (14 - kk) * 1024;
      const float scale = 1.0f / (5120.0f * (float)(14 - kk));
      for (int e = t; e < Mk; e += 256)
        local += Lk[kk * 14336 + e] * scale;
    }
    red[t] = local;
    __syncthreads();
    for (int s = 128; s; s >>= 1) {
      if (t < s) red[t] += red[t + s];
      __syncthreads();
    }
    if (t == 0) out[0] = red[0];
  }
}

extern "C" void kernel_launch(void* const* d_in, const int* in_sizes, int n_in,
                              void* d_out, int out_size, void* d_ws, size_t ws_size,
                              hipStream_t stream) {
  const float* z  = (const float*)d_in[0];
  const float* c  = (const float*)d_in[1];
  const float* Wk = (const float*)d_in[2];
  float* out = (float*)d_out;
  char* wsb = (char*)d_ws;
  unsigned short* Zp = (unsigned short*)(wsb);
  unsigned short* Cb = (unsigned short*)(wsb + 8388608);
  unsigned short* Wb = (unsigned short*)(wsb + 16777216);
  unsigned short* Yb = (unsigned short*)(wsb + 17432576);
  float*          Lk = (float*)(wsb + 54132736);

  prep_all<<<dim3(256, 8, 2), 256, 0, stream>>>(z, c, Wk, Zp, Cb, Wb);
  gemm_all<<<dim3(2, 112, PRED_), 256, 0, stream>>>(Zp, Wb, Yb);
  score_all<<<3840, 256, 0, stream>>>(
      Yb, Cb, (const int*)d_in[3], (const int*)d_in[4], (const int*)d_in[5],
      (const int*)d_in[6], (const int*)d_in[7], Lk);
  finalize_pl<<<65, 256, 0, stream>>>(Lk, out);
}